// Round 1
// baseline (618.312 us; speedup 1.0000x reference)
//
#include <hip/hip_runtime.h>
#include <hip/hip_bf16.h>
#include <stdint.h>
#include <math.h>

#define NTOK  2048
#define HDIM  1024
#define FDIM  768
#define NEXP  32
#define TOPK  8
#define CAP   1024

typedef __attribute__((ext_vector_type(8))) short short8;
typedef __attribute__((ext_vector_type(4))) float f32x4;

__device__ __forceinline__ short f2bf(float f) {
  union { float f; uint32_t u; } c; c.f = f;
  uint32_t u = c.u;
  u += 0x7fffu + ((u >> 16) & 1u);   // RNE
  return (short)(u >> 16);
}

__device__ __forceinline__ short8 pack8(float4 a, float4 b) {
  short8 r;
  r[0] = f2bf(a.x); r[1] = f2bf(a.y); r[2] = f2bf(a.z); r[3] = f2bf(a.w);
  r[4] = f2bf(b.x); r[5] = f2bf(b.y); r[6] = f2bf(b.z); r[7] = f2bf(b.w);
  return r;
}

// ---------------- router: logits (fp32), top-8, renorm weights, scatter, x->bf16 ----------------
__global__ __launch_bounds__(256) void router_kern(
    const float* __restrict__ x, const float* __restrict__ gw,
    int* __restrict__ cnt, int* __restrict__ slot_tok,
    float* __restrict__ slot_w, short* __restrict__ xb) {
  const int n0 = blockIdx.x * 8;      // 8 tokens per block, grid = 256
  const int t  = threadIdx.x;
  __shared__ float ls[8][32];

  // thread t handles expert e = t>>3, k-residue j = t&7
  const int e = t >> 3;
  const int j = t & 7;
  float acc[8];
#pragma unroll
  for (int i = 0; i < 8; ++i) acc[i] = 0.f;
  const float* gwe = gw + (size_t)e * HDIM;
  for (int i = 0; i < 128; ++i) {
    const int k = j + 8 * i;
    const float gv = gwe[k];
#pragma unroll
    for (int tok = 0; tok < 8; ++tok)
      acc[tok] += gv * x[(size_t)(n0 + tok) * HDIM + k];
  }
  // reduce over j (groups of 8 lanes within the wave)
#pragma unroll
  for (int tok = 0; tok < 8; ++tok) {
    float v = acc[tok];
    v += __shfl_xor(v, 1); v += __shfl_xor(v, 2); v += __shfl_xor(v, 4);
    if (j == 0) ls[tok][e] = v;
  }
  __syncthreads();

  // top-8 + renormalized softmax weights + scatter (one thread per token)
  if (t < 8) {
    const int n = n0 + t;
    float lv[32];
#pragma unroll
    for (int i = 0; i < 32; ++i) lv[i] = ls[t][i];
    int   idx[TOPK];
    float val[TOPK];
    for (int kk = 0; kk < TOPK; ++kk) {
      float best = -INFINITY; int bi = 0;
      for (int i = 0; i < 32; ++i)
        if (lv[i] > best) { best = lv[i]; bi = i; }   // strict > : first-index tie-break (matches top_k)
      val[kk] = best; idx[kk] = bi; lv[bi] = -INFINITY;
    }
    const float m = val[0];
    float w[TOPK]; float wsum = 0.f;
    for (int kk = 0; kk < TOPK; ++kk) { w[kk] = __expf(val[kk] - m); wsum += w[kk]; }
    const float inv = 1.f / wsum;     // softmax over top-8 == softmax-all then renorm (denominators cancel)
    for (int kk = 0; kk < TOPK; ++kk) {
      const int ee = idx[kk];
      const int pos = atomicAdd(&cnt[ee], 1);
      if (pos < CAP) {
        slot_tok[ee * CAP + pos] = n * TOPK + kk;   // slot id
        slot_w[ee * CAP + pos]   = w[kk] * inv;
      }
    }
  }

  // x -> bf16 for MFMA A operand
  const size_t base = (size_t)n0 * HDIM;
  for (int i = t; i < 8 * HDIM; i += 256)
    xb[base + i] = f2bf(x[base + i]);
}

// ---------------- GEMM1: h = silu(x@Wg^T) * (x@Wu^T), per expert ----------------
__global__ __launch_bounds__(256) void gemm1_kern(
    const short* __restrict__ xb, const float* __restrict__ gup,
    const int* __restrict__ cnt, const int* __restrict__ slot_tok,
    short* __restrict__ hbuf) {
  const int e = blockIdx.z;
  const int mcnt = min(cnt[e], CAP);
  const int r0 = blockIdx.y * 64;
  if (r0 >= mcnt) return;
  const int f0 = blockIdx.x * 64;

  __shared__ short As[64 * 32];
  __shared__ short Bs[128 * 32];   // rows 0..63: gate, 64..127: up

  const int t = threadIdx.x;
  const int ar = t >> 2;           // staging row (0..63)
  const int koff = (t & 3) * 8;    // staging k-offset (8 elems)

  const short* aptr = nullptr;
  const bool avalid = (r0 + ar) < mcnt;
  if (avalid) {
    const int n = slot_tok[e * CAP + r0 + ar] >> 3;   // token id
    aptr = xb + (size_t)n * HDIM + koff;
  }
  const float* gp  = gup + ((size_t)e * (2 * FDIM) + (f0 + ar)) * HDIM + koff;
  const float* upp = gup + ((size_t)e * (2 * FDIM) + (FDIM + f0 + ar)) * HDIM + koff;

  const int wave = t >> 6, lane = t & 63;
  const int wm = (wave & 1) * 32, wf = (wave >> 1) * 32;
  const int lrow = lane & 15, lk = (lane >> 4) * 8;

  f32x4 accg[2][2], accu[2][2];
#pragma unroll
  for (int a = 0; a < 2; ++a)
#pragma unroll
    for (int b = 0; b < 2; ++b) {
      accg[a][b] = (f32x4){0.f, 0.f, 0.f, 0.f};
      accu[a][b] = (f32x4){0.f, 0.f, 0.f, 0.f};
    }

  for (int kb = 0; kb < HDIM; kb += 32) {
    if (avalid) *(uint4*)&As[ar * 32 + koff] = *(const uint4*)(aptr + kb);
    else        *(uint4*)&As[ar * 32 + koff] = make_uint4(0, 0, 0, 0);
    const float4 g0 = *(const float4*)(gp + kb);
    const float4 g1 = *(const float4*)(gp + kb + 4);
    const float4 u0 = *(const float4*)(upp + kb);
    const float4 u1 = *(const float4*)(upp + kb + 4);
    *(short8*)&Bs[ar * 32 + koff]        = pack8(g0, g1);
    *(short8*)&Bs[(64 + ar) * 32 + koff] = pack8(u0, u1);
    __syncthreads();

    short8 af[2], bg[2], bu[2];
    af[0] = *(const short8*)&As[(wm + lrow) * 32 + lk];
    af[1] = *(const short8*)&As[(wm + 16 + lrow) * 32 + lk];
    bg[0] = *(const short8*)&Bs[(wf + lrow) * 32 + lk];
    bg[1] = *(const short8*)&Bs[(wf + 16 + lrow) * 32 + lk];
    bu[0] = *(const short8*)&Bs[(64 + wf + lrow) * 32 + lk];
    bu[1] = *(const short8*)&Bs[(64 + wf + 16 + lrow) * 32 + lk];
#pragma unroll
    for (int mt = 0; mt < 2; ++mt)
#pragma unroll
      for (int nt = 0; nt < 2; ++nt) {
        accg[mt][nt] = __builtin_amdgcn_mfma_f32_16x16x32_bf16(af[mt], bg[nt], accg[mt][nt], 0, 0, 0);
        accu[mt][nt] = __builtin_amdgcn_mfma_f32_16x16x32_bf16(af[mt], bu[nt], accu[mt][nt], 0, 0, 0);
      }
    __syncthreads();
  }

  // epilogue: silu(g)*u -> bf16 h[e][pos][f]
#pragma unroll
  for (int mt = 0; mt < 2; ++mt)
#pragma unroll
    for (int nt = 0; nt < 2; ++nt)
#pragma unroll
      for (int r = 0; r < 4; ++r) {
        const int pos = r0 + wm + mt * 16 + (lane >> 4) * 4 + r;
        if (pos < mcnt) {
          const int f = f0 + wf + nt * 16 + (lane & 15);
          const float g = accg[mt][nt][r];
          const float u = accu[mt][nt][r];
          const float hv = (g / (1.f + __expf(-g))) * u;
          hbuf[((size_t)e * CAP + pos) * FDIM + f] = f2bf(hv);
        }
      }
}

// ---------------- GEMM2: slot_out[s] = w_s * (h @ Wd^T) ----------------
__global__ __launch_bounds__(256) void gemm2_kern(
    const short* __restrict__ hbuf, const float* __restrict__ dwn,
    const int* __restrict__ cnt, const int* __restrict__ slot_tok,
    const float* __restrict__ slot_w, float* __restrict__ slot_out) {
  const int e = blockIdx.z;
  const int mcnt = min(cnt[e], CAP);
  const int r0 = blockIdx.y * 64;
  if (r0 >= mcnt) return;
  const int n0 = blockIdx.x * 64;

  __shared__ short As[64 * 32];
  __shared__ short Bs[64 * 32];

  const int t = threadIdx.x;
  const int ar = t >> 2;
  const int koff = (t & 3) * 8;

  const short* aptr = hbuf + ((size_t)e * CAP + (r0 + ar)) * FDIM + koff;
  const float* bp   = dwn + ((size_t)e * HDIM + (n0 + ar)) * FDIM + koff;

  const int wave = t >> 6, lane = t & 63;
  const int wm = (wave & 1) * 32, wn = (wave >> 1) * 32;
  const int lrow = lane & 15, lk = (lane >> 4) * 8;

  f32x4 acc[2][2];
#pragma unroll
  for (int a = 0; a < 2; ++a)
#pragma unroll
    for (int b = 0; b < 2; ++b) acc[a][b] = (f32x4){0.f, 0.f, 0.f, 0.f};

  for (int kb = 0; kb < FDIM; kb += 32) {
    *(uint4*)&As[ar * 32 + koff] = *(const uint4*)(aptr + kb);
    const float4 b0 = *(const float4*)(bp + kb);
    const float4 b1 = *(const float4*)(bp + kb + 4);
    *(short8*)&Bs[ar * 32 + koff] = pack8(b0, b1);
    __syncthreads();

    short8 af[2], bf[2];
    af[0] = *(const short8*)&As[(wm + lrow) * 32 + lk];
    af[1] = *(const short8*)&As[(wm + 16 + lrow) * 32 + lk];
    bf[0] = *(const short8*)&Bs[(wn + lrow) * 32 + lk];
    bf[1] = *(const short8*)&Bs[(wn + 16 + lrow) * 32 + lk];
#pragma unroll
    for (int mt = 0; mt < 2; ++mt)
#pragma unroll
      for (int nt = 0; nt < 2; ++nt)
        acc[mt][nt] = __builtin_amdgcn_mfma_f32_16x16x32_bf16(af[mt], bf[nt], acc[mt][nt], 0, 0, 0);
    __syncthreads();
  }

#pragma unroll
  for (int mt = 0; mt < 2; ++mt)
#pragma unroll
    for (int nt = 0; nt < 2; ++nt)
#pragma unroll
      for (int r = 0; r < 4; ++r) {
        const int pos = r0 + wm + mt * 16 + (lane >> 4) * 4 + r;
        if (pos < mcnt) {
          const int s = slot_tok[e * CAP + pos];
          const float w = slot_w[e * CAP + pos];
          const int col = n0 + wn + nt * 16 + (lane & 15);
          slot_out[(size_t)s * HDIM + col] = w * acc[mt][nt][r];
        }
      }
}

// ---------------- gather: out[n] = sum_k slot_out[n*8+k] ----------------
__global__ __launch_bounds__(256) void gather_kern(
    const float* __restrict__ so, float* __restrict__ out) {
  const int n = blockIdx.x;
  const int c = threadIdx.x * 4;
  float4 a = make_float4(0.f, 0.f, 0.f, 0.f);
#pragma unroll
  for (int k = 0; k < TOPK; ++k) {
    const float4 v = *(const float4*)&so[((size_t)(n * TOPK + k)) * HDIM + c];
    a.x += v.x; a.y += v.y; a.z += v.z; a.w += v.w;
  }
  *(float4*)&out[(size_t)n * HDIM + c] = a;
}

extern "C" void kernel_launch(void* const* d_in, const int* in_sizes, int n_in,
                              void* d_out, int out_size, void* d_ws, size_t ws_size,
                              hipStream_t stream) {
  const float* x   = (const float*)d_in[0];
  const float* gw  = (const float*)d_in[1];
  const float* gup = (const float*)d_in[2];
  const float* dwn = (const float*)d_in[3];
  float* out = (float*)d_out;

  char* ws = (char*)d_ws;
  // layout: cnt(1KB) | slot_tok(128KB) | slot_w(128KB) | pad | xb(4MB) | h(48MB) | slot_out(64MB)
  int*   cnt      = (int*)(ws + 0);
  int*   slot_tok = (int*)(ws + 1024);
  float* slot_w   = (float*)(ws + 1024 + 131072);
  short* xb       = (short*)(ws + 524288);
  short* hbuf     = (short*)(ws + 524288 + 4194304);
  float* slot_out = (float*)(ws + 524288 + 4194304 + 50331648);

  hipMemsetAsync(cnt, 0, 1024, stream);
  router_kern<<<NTOK / 8, 256, 0, stream>>>(x, gw, cnt, slot_tok, slot_w, xb);
  gemm1_kern<<<dim3(FDIM / 64, CAP / 64, NEXP), 256, 0, stream>>>(xb, gup, cnt, slot_tok, hbuf);
  gemm2_kern<<<dim3(HDIM / 64, CAP / 64, NEXP), 256, 0, stream>>>(hbuf, dwn, cnt, slot_tok, slot_w, slot_out);
  gather_kern<<<NTOK, 256, 0, stream>>>(slot_out, out);
}